// Round 3
// baseline (129.175 us; speedup 1.0000x reference)
//
#include <hip/hip_runtime.h>
#include <hip/hip_fp16.h>
#include <math.h>

#define N_NODE 50000
#define D_FEAT 128
#define N_EDGE 625000
#define SIM_THRESH 0.1f
// int8 screen: dot-error std ~3.2e-3; 0.02 margin is ~6 sigma.
// (fp8 screen fallback: std ~3.4e-3; same margin.)
#define SCREEN_LO 0.08f
// fp16 sim error std ~3.5e-5; 5e-4 band is ~14x margin.
#define BAND_EPS 5e-4f

typedef float v2f __attribute__((ext_vector_type(2)));
typedef int   v4i __attribute__((ext_vector_type(4)));
typedef float v4f __attribute__((ext_vector_type(4)));

#if __has_builtin(__builtin_amdgcn_sdot4)
#define USE_SDOT4 1
#else
#define USE_SDOT4 0
#endif

#if __has_builtin(__builtin_amdgcn_fdot2)
#define USE_FDOT2 1
typedef _Float16 h2v __attribute__((ext_vector_type(2)));
#else
#define USE_FDOT2 0
#endif

// ===========================================================================
// K1: per-node inv-norm; normalized fp16 value table + int8 (or fp8) screen
// table; zero row_sum/degree (ws poisoned 0xAA). 32 lanes/node.
// ===========================================================================
__global__ void prep_kernel(const float* __restrict__ feat,
                            float* __restrict__ inv_nrm,
                            __half* __restrict__ fn16,
                            unsigned int* __restrict__ qtab,
                            float* __restrict__ row_sum,
                            float* __restrict__ degree) {
    int g = blockIdx.x * blockDim.x + threadIdx.x;
    if (g < N_NODE) { row_sum[g] = 0.0f; degree[g] = 0.0f; }
    int node = g >> 5;
    int lane = g & 31;
    if (node >= N_NODE) return;
    float4 v = ((const float4*)(feat + (size_t)node * D_FEAT))[lane];
    float ss = v.x * v.x + v.y * v.y + v.z * v.z + v.w * v.w;
#pragma unroll
    for (int o = 16; o > 0; o >>= 1) ss += __shfl_xor(ss, o, 32);
    float inv = 1.0f / fmaxf(sqrtf(ss), 1e-12f);
    if (lane == 0) inv_nrm[node] = inv;
    float x0 = v.x * inv, x1 = v.y * inv, x2 = v.z * inv, x3 = v.w * inv;
    __half2 h0 = __floats2half2_rn(x0, x1);
    __half2 h1 = __floats2half2_rn(x2, x3);
    uint2 p;
    p.x = *(unsigned int*)&h0;
    p.y = *(unsigned int*)&h1;
    ((uint2*)(fn16 + (size_t)node * D_FEAT))[lane] = p;
#if USE_SDOT4
    // int8 symmetric quant: x in [-1,1] -> [-127,127], exact fit.
    int q0 = (int)rintf(x0 * 127.0f);
    int q1 = (int)rintf(x1 * 127.0f);
    int q2 = (int)rintf(x2 * 127.0f);
    int q3 = (int)rintf(x3 * 127.0f);
    unsigned int w = (unsigned int)(q0 & 0xff) | ((unsigned int)(q1 & 0xff) << 8) |
                     ((unsigned int)(q2 & 0xff) << 16) | ((unsigned int)(q3 & 0xff) << 24);
#else
    int wi = __builtin_amdgcn_cvt_pk_fp8_f32(x0, x1, 0, false);
    wi = __builtin_amdgcn_cvt_pk_fp8_f32(x2, x3, wi, true);
    unsigned int w = (unsigned int)wi;
#endif
    qtab[(size_t)node * 32 + lane] = w;
}

// ===========================================================================
// K2: per-edge sim, 8 lanes/edge (8 edges per wave). Three-tier precision:
//   int8 sdot4 screen (uint4/lane) -> fp16 fdot2 value (sim8 > 0.08, ~18%)
//                                  -> fp32 exact (|sim16-0.1| < 5e-4, ~0.25%)
//
// Cache-policy theory (this round): avg degree 12.5 -> qtab rows re-read ~25x,
// fn16 rows ~4.5x. Per-XCD L2 (4MB) < working set (32MB, random node idx), so
// LRU lets the colder fn16 stream evict the hot 6.4MB qtab. Mark tier-2/3
// gathers NONTEMPORAL (evict-first in L2) so qtab stays resident; tier-1
// loads keep normal policy. VALU count is NOT the limit (R2 null result).
// ===========================================================================
__global__ __launch_bounds__(256)
void edge_sim8_kernel(const int* __restrict__ row,
                      const int* __restrict__ col,
                      const float* __restrict__ feat,
                      const float* __restrict__ inv_nrm,
                      const __half* __restrict__ fn16,
                      const unsigned int* __restrict__ qtab,
                      float* __restrict__ sim_out,
                      float* __restrict__ row_sum,
                      float* __restrict__ degree) {
    int g = blockIdx.x * blockDim.x + threadIdx.x;
    int edge = g >> 3;
    int lane = g & 7;
    if (edge >= N_EDGE) return;
    // streamed once: nontemporal so they don't evict the gather tables from L2
    int r = __builtin_nontemporal_load(row + edge);
    int c = __builtin_nontemporal_load(col + edge);

    // --- tier 1: low-precision screen, 16 B/lane per endpoint (one 128B line/row)
    //     NORMAL cache policy: hottest table, want it L2-resident.
    uint4 aw = ((const uint4*)(qtab + (size_t)r * 32))[lane];
    uint4 bw = ((const uint4*)(qtab + (size_t)c * 32))[lane];
    float d;
#if USE_SDOT4
    {
        const unsigned int* awp = (const unsigned int*)&aw;
        const unsigned int* bwp = (const unsigned int*)&bw;
        int acc = 0;
#pragma unroll
        for (int i = 0; i < 4; i++)
            acc = __builtin_amdgcn_sdot4((int)awp[i], (int)bwp[i], acc, false);
#pragma unroll
        for (int o = 4; o > 0; o >>= 1) acc += __shfl_xor(acc, o, 8);
        d = (float)acc * (1.0f / 16129.0f);   // 1/127^2
    }
#else
    {
        const unsigned int* awp = (const unsigned int*)&aw;
        const unsigned int* bwp = (const unsigned int*)&bw;
        d = 0.0f;
#pragma unroll
        for (int i = 0; i < 4; i++) {
            v2f alo = __builtin_amdgcn_cvt_pk_f32_fp8((int)awp[i], false);
            v2f ahi = __builtin_amdgcn_cvt_pk_f32_fp8((int)awp[i], true);
            v2f blo = __builtin_amdgcn_cvt_pk_f32_fp8((int)bwp[i], false);
            v2f bhi = __builtin_amdgcn_cvt_pk_f32_fp8((int)bwp[i], true);
            d = fmaf(alo.x, blo.x, d); d = fmaf(alo.y, blo.y, d);
            d = fmaf(ahi.x, bhi.x, d); d = fmaf(ahi.y, bhi.y, d);
        }
#pragma unroll
        for (int o = 4; o > 0; o >>= 1) d += __shfl_xor(d, o, 8);
    }
#endif
    // xor butterfly leaves identical sum in all 8 lanes -> group-uniform branch

    float s = 0.0f;
    if (d > SCREEN_LO) {
        // --- tier 2: fp16 value, 32 B/lane per endpoint. NONTEMPORAL:
        //     colder than qtab; don't let it evict qtab from L2.
        const v4f* ar = (const v4f*)(fn16 + (size_t)r * D_FEAT);
        const v4f* br = (const v4f*)(fn16 + (size_t)c * D_FEAT);
        v4f a0 = __builtin_nontemporal_load(ar + lane);
        v4f a1 = __builtin_nontemporal_load(ar + lane + 8);
        v4f b0 = __builtin_nontemporal_load(br + lane);
        v4f b1 = __builtin_nontemporal_load(br + lane + 8);
        float dh = 0.0f;
#if USE_FDOT2
        {
            const h2v* ah0 = (const h2v*)&a0;
            const h2v* bh0 = (const h2v*)&b0;
            const h2v* ah1 = (const h2v*)&a1;
            const h2v* bh1 = (const h2v*)&b1;
#pragma unroll
            for (int i = 0; i < 4; i++) {
                dh = __builtin_amdgcn_fdot2(ah0[i], bh0[i], dh, false);
                dh = __builtin_amdgcn_fdot2(ah1[i], bh1[i], dh, false);
            }
        }
#else
        {
            const __half2* ah0 = (const __half2*)&a0;
            const __half2* bh0 = (const __half2*)&b0;
            const __half2* ah1 = (const __half2*)&a1;
            const __half2* bh1 = (const __half2*)&b1;
#pragma unroll
            for (int i = 0; i < 4; i++) {
                float2 afv = __half22float2(ah0[i]);
                float2 bfv = __half22float2(bh0[i]);
                dh = fmaf(afv.x, bfv.x, dh);
                dh = fmaf(afv.y, bfv.y, dh);
                float2 afw = __half22float2(ah1[i]);
                float2 bfw = __half22float2(bh1[i]);
                dh = fmaf(afw.x, bfw.x, dh);
                dh = fmaf(afw.y, bfw.y, dh);
            }
        }
#endif
#pragma unroll
        for (int o = 4; o > 0; o >>= 1) dh += __shfl_xor(dh, o, 8);
        if (fabsf(dh - SIM_THRESH) < BAND_EPS) {
            // --- tier 3: exact fp32 (rare ~0.25%). NONTEMPORAL: no reuse value.
            const v4f* fr = (const v4f*)(feat + (size_t)r * D_FEAT);
            const v4f* fc = (const v4f*)(feat + (size_t)c * D_FEAT);
            float dd = 0.0f;
#pragma unroll
            for (int q = 0; q < 4; q++) {
                v4f av = __builtin_nontemporal_load(fr + lane + q * 8);
                v4f bv = __builtin_nontemporal_load(fc + lane + q * 8);
                dd += av.x * bv.x + av.y * bv.y + av.z * bv.z + av.w * bv.w;
            }
#pragma unroll
            for (int o = 4; o > 0; o >>= 1) dd += __shfl_xor(dd, o, 8);
            dh = dd * inv_nrm[r] * inv_nrm[c];
        }
        s = (dh < SIM_THRESH) ? 0.0f : dh;
    }
    if (lane == 0) {
        sim_out[edge] = s;
        if (s != 0.0f) {
            atomicAdd(&row_sum[r], s);
            atomicAdd(&degree[r], 1.0f);
        }
    }
}

// ===========================================================================
// K3: epilogue — normalize, diagonal lam, exp, gate blend, clamp.
// 4 edges/thread (N_EDGE % 4 == 0), vectorized nontemporal streams.
// NOTE: __builtin_nontemporal_* requires clang ext_vector types (v4i/v4f),
// NOT HIP_vector_type int4/float4 (compile error).
// ===========================================================================
__global__ void edge_out_kernel(const int* __restrict__ row,
                                const int* __restrict__ col,
                                const float* __restrict__ sim,
                                const float* __restrict__ row_sum,
                                const float* __restrict__ degree,
                                const float* __restrict__ ew,
                                const float* __restrict__ gate,
                                float* __restrict__ out) {
    int t = blockIdx.x * blockDim.x + threadIdx.x;
    if (t >= N_EDGE / 4) return;
    v4i r4 = __builtin_nontemporal_load((const v4i*)row + t);
    v4i c4 = __builtin_nontemporal_load((const v4i*)col + t);
    v4f s4 = __builtin_nontemporal_load((const v4f*)sim + t);
    v4f w4 = __builtin_nontemporal_load((const v4f*)ew + t);
    float gv = gate[0];
    float og = 1.0f - gv;
    v4f o4;
#pragma unroll
    for (int i = 0; i < 4; i++) {
        int   ri = r4[i];
        float rs = row_sum[ri];
        float att = s4[i] / ((rs > 0.0f) ? rs : 1.0f);
        if (ri == c4[i]) att += 1.0f / (degree[ri] + 1.0f);
        o4[i] = fmaxf(gv * w4[i] + og * expf(att), 0.0f);
    }
    __builtin_nontemporal_store(o4, (v4f*)out + t);
}

// ===========================================================================
// Fallback (pure fp32) if ws too small.
// ===========================================================================
__global__ void inv_norm_kernel(const float* __restrict__ feat,
                                float* __restrict__ inv_nrm,
                                float* __restrict__ row_sum,
                                float* __restrict__ degree) {
    int g = blockIdx.x * blockDim.x + threadIdx.x;
    if (g < N_NODE) { row_sum[g] = 0.0f; degree[g] = 0.0f; }
    int node = g >> 5;
    int lane = g & 31;
    if (node >= N_NODE) return;
    float4 v = ((const float4*)(feat + (size_t)node * D_FEAT))[lane];
    float ss = v.x * v.x + v.y * v.y + v.z * v.z + v.w * v.w;
#pragma unroll
    for (int o = 16; o > 0; o >>= 1) ss += __shfl_down(ss, o, 32);
    if (lane == 0) inv_nrm[node] = 1.0f / fmaxf(sqrtf(ss), 1e-12f);
}

__global__ void edge_sim_kernel(const int* __restrict__ row,
                                const int* __restrict__ col,
                                const float* __restrict__ feat,
                                const float* __restrict__ inv_nrm,
                                float* __restrict__ sim_out,
                                float* __restrict__ row_sum,
                                float* __restrict__ degree) {
    int g = blockIdx.x * blockDim.x + threadIdx.x;
    int edge = g >> 5;
    int lane = g & 31;
    if (edge >= N_EDGE) return;
    int r = row[edge];
    int c = col[edge];
    float4 a = ((const float4*)(feat + (size_t)r * D_FEAT))[lane];
    float4 b = ((const float4*)(feat + (size_t)c * D_FEAT))[lane];
    float d = a.x * b.x + a.y * b.y + a.z * b.z + a.w * b.w;
#pragma unroll
    for (int o = 16; o > 0; o >>= 1) d += __shfl_down(d, o, 32);
    if (lane == 0) {
        float s = d * inv_nrm[r] * inv_nrm[c];
        if (s < SIM_THRESH) s = 0.0f;
        sim_out[edge] = s;
        if (s != 0.0f) {
            atomicAdd(&row_sum[r], s);
            atomicAdd(&degree[r], 1.0f);
        }
    }
}

// ===========================================================================
// Launch — 3 dispatches. Journal constraints baked in:
//  - grid.sync costs ~600us on MI355X (R3): never fuse across the reduction.
//  - CSR/bucket permutation passes cost more than the <=24MB dedup they can
//    win (R5, R6): keep the edge order as-given.
//  - top-5 rocprof dispatches are all 268MB ws re-poison fills (~44us each,
//    ~76% HBM peak) — harness machinery, not addressable from the kernel.
//  - R2: 3x VALU cut in K2 (sdot4/fdot2) = ZERO delta -> K2 not issue-bound.
//    This round discriminates L2-thrash vs fixed-overhead via nt policy.
// ===========================================================================
extern "C" void kernel_launch(void* const* d_in, const int* in_sizes, int n_in,
                              void* d_out, int out_size, void* d_ws, size_t ws_size,
                              hipStream_t stream) {
    const int*   edge_index = (const int*)d_in[0];   // [2, E]: row then col
    const float* ew         = (const float*)d_in[1];
    const float* feat       = (const float*)d_in[2];
    const float* gate       = (const float*)d_in[3];
    float*       out        = (float*)d_out;

    const int* row = edge_index;
    const int* col = edge_index + N_EDGE;

    // ws layout: row_sum[N] | degree[N] | inv_nrm[N] | sim[E]
    //            | fn16[N*128 halves] | qtab[N*32 uints]
    float* row_sum = (float*)d_ws;
    float* degree  = row_sum + N_NODE;
    float* inv_nrm = degree + N_NODE;
    float* sim     = inv_nrm + N_NODE;
    __half* fn16   = (__half*)(sim + N_EDGE);
    unsigned int* qtab = (unsigned int*)(fn16 + (size_t)N_NODE * D_FEAT);

    size_t need = (size_t)(3 * N_NODE + N_EDGE) * 4
                + (size_t)N_NODE * D_FEAT * 2
                + (size_t)N_NODE * D_FEAT;

    const int block = 256;

    if (ws_size >= need) {
        {
            long long threads = (long long)N_NODE * 32;
            prep_kernel<<<(int)((threads + block - 1) / block), block, 0, stream>>>(
                feat, inv_nrm, fn16, qtab, row_sum, degree);
        }
        {
            long long threads = (long long)N_EDGE * 8;
            edge_sim8_kernel<<<(int)((threads + block - 1) / block), block, 0, stream>>>(
                row, col, feat, inv_nrm, fn16, qtab, sim, row_sum, degree);
        }
        {
            int threads = N_EDGE / 4;
            edge_out_kernel<<<(threads + block - 1) / block, block, 0, stream>>>(
                row, col, sim, row_sum, degree, ew, gate, out);
        }
    } else {
        {
            long long threads = (long long)N_NODE * 32;
            inv_norm_kernel<<<(int)((threads + block - 1) / block), block, 0, stream>>>(
                feat, inv_nrm, row_sum, degree);
        }
        {
            long long threads = (long long)N_EDGE * 32;
            edge_sim_kernel<<<(int)((threads + block - 1) / block), block, 0, stream>>>(
                row, col, feat, inv_nrm, sim, row_sum, degree);
        }
        {
            int threads = N_EDGE / 4;
            edge_out_kernel<<<(threads + block - 1) / block, block, 0, stream>>>(
                row, col, sim, row_sum, degree, ew, gate, out);
        }
    }
}

// Round 4
// 126.400 us; speedup vs baseline: 1.0220x; 1.0220x over previous
//
#include <hip/hip_runtime.h>
#include <hip/hip_fp16.h>
#include <math.h>

#define N_NODE 50000
#define D_FEAT 128
#define N_EDGE 625000
#define SIM_THRESH 0.1f
// int8 screen: dot-error std ~3.2e-3; 0.02 margin is ~6 sigma.
#define SCREEN_LO 0.08f
// fp16 sim error std ~3.5e-5; 5e-4 band is ~14x margin.
#define BAND_EPS 5e-4f

typedef float v2f __attribute__((ext_vector_type(2)));
typedef int   v4i __attribute__((ext_vector_type(4)));
typedef float v4f __attribute__((ext_vector_type(4)));

#if __has_builtin(__builtin_amdgcn_sdot4)
#define USE_SDOT4 1
#else
#define USE_SDOT4 0
#endif

#if __has_builtin(__builtin_amdgcn_fdot2)
#define USE_FDOT2 1
typedef _Float16 h2v __attribute__((ext_vector_type(2)));
#else
#define USE_FDOT2 0
#endif

// ===========================================================================
// K1: per-node inv-norm; normalized fp16 value table + int8 screen table;
// zero row_sum/degree (ws poisoned 0xAA). 32 lanes/node.
// ===========================================================================
__global__ void prep_kernel(const float* __restrict__ feat,
                            float* __restrict__ inv_nrm,
                            __half* __restrict__ fn16,
                            unsigned int* __restrict__ qtab,
                            float* __restrict__ row_sum,
                            float* __restrict__ degree) {
    int g = blockIdx.x * blockDim.x + threadIdx.x;
    if (g < N_NODE) { row_sum[g] = 0.0f; degree[g] = 0.0f; }
    int node = g >> 5;
    int lane = g & 31;
    if (node >= N_NODE) return;
    float4 v = ((const float4*)(feat + (size_t)node * D_FEAT))[lane];
    float ss = v.x * v.x + v.y * v.y + v.z * v.z + v.w * v.w;
#pragma unroll
    for (int o = 16; o > 0; o >>= 1) ss += __shfl_xor(ss, o, 32);
    float inv = 1.0f / fmaxf(sqrtf(ss), 1e-12f);
    if (lane == 0) inv_nrm[node] = inv;
    float x0 = v.x * inv, x1 = v.y * inv, x2 = v.z * inv, x3 = v.w * inv;
    __half2 h0 = __floats2half2_rn(x0, x1);
    __half2 h1 = __floats2half2_rn(x2, x3);
    uint2 p;
    p.x = *(unsigned int*)&h0;
    p.y = *(unsigned int*)&h1;
    ((uint2*)(fn16 + (size_t)node * D_FEAT))[lane] = p;
#if USE_SDOT4
    int q0 = (int)rintf(x0 * 127.0f);
    int q1 = (int)rintf(x1 * 127.0f);
    int q2 = (int)rintf(x2 * 127.0f);
    int q3 = (int)rintf(x3 * 127.0f);
    unsigned int w = (unsigned int)(q0 & 0xff) | ((unsigned int)(q1 & 0xff) << 8) |
                     ((unsigned int)(q2 & 0xff) << 16) | ((unsigned int)(q3 & 0xff) << 24);
#else
    int wi = __builtin_amdgcn_cvt_pk_fp8_f32(x0, x1, 0, false);
    wi = __builtin_amdgcn_cvt_pk_fp8_f32(x2, x3, wi, true);
    unsigned int w = (unsigned int)wi;
#endif
    qtab[(size_t)node * 32 + lane] = w;
}

// ===========================================================================
// K2 v2: 4 edges per 8-lane group ("EPT=4") for gather MLP.
//
// R3 diagnosis: 43.8us, 34% HBM, 17.5% VALU, occ 62% -> latency/MLP-bound,
// traffic already near compulsory (117MB ~= qtab*8XCD + touched fn16*8XCD).
// Old structure had only 2 gathers in flight, then a serial tier-2 phase.
// New structure:
//   - 8 tier-1 qtab gathers issued back-to-back (4 edges x {r,c})
//   - tier-2 is BRANCHLESS-speculative: non-passing edges read node 0's row
//     (L2-hot fallback -> no extra HBM/L3 traffic), so all 16 tier-2 loads
//     for the group issue together with no cross-k serialization.
//   - independent shuffle-reduces for the 4 edges interleave (hide DS lat).
//   - stores/atomics spread across lanes 0..3.
// VGPR ~90-100: 2048/100 ~= 20 waves/CU = measured occupancy -> no loss.
// ===========================================================================
__global__ __launch_bounds__(256)
void edge_sim8_kernel(const int* __restrict__ row,
                      const int* __restrict__ col,
                      const float* __restrict__ feat,
                      const float* __restrict__ inv_nrm,
                      const __half* __restrict__ fn16,
                      const unsigned int* __restrict__ qtab,
                      float* __restrict__ sim_out,
                      float* __restrict__ row_sum,
                      float* __restrict__ degree) {
    int g = blockIdx.x * blockDim.x + threadIdx.x;
    int grp = g >> 3;            // each group: edges 4*grp .. 4*grp+3
    int lane = g & 7;
    if (grp >= N_EDGE / 4) return;
    size_t e0 = (size_t)grp * 4;

    // indices: lanes 0-3 load row[e0..e0+3], lanes 4-7 load col[e0..e0+3]
    int idx = __builtin_nontemporal_load(
        row + (size_t)(lane >> 2) * N_EDGE + e0 + (lane & 3));
    int r0 = __shfl(idx, 0, 8), r1 = __shfl(idx, 1, 8);
    int r2 = __shfl(idx, 2, 8), r3 = __shfl(idx, 3, 8);
    int c0 = __shfl(idx, 4, 8), c1 = __shfl(idx, 5, 8);
    int c2 = __shfl(idx, 6, 8), c3 = __shfl(idx, 7, 8);

    // --- tier 1: 8 independent 16B gathers, all in flight ---
    const uint4* q = (const uint4*)qtab;   // 8 uint4 per node row
    uint4 aw0 = q[(size_t)r0 * 8 + lane];
    uint4 aw1 = q[(size_t)r1 * 8 + lane];
    uint4 aw2 = q[(size_t)r2 * 8 + lane];
    uint4 aw3 = q[(size_t)r3 * 8 + lane];
    uint4 bw0 = q[(size_t)c0 * 8 + lane];
    uint4 bw1 = q[(size_t)c1 * 8 + lane];
    uint4 bw2 = q[(size_t)c2 * 8 + lane];
    uint4 bw3 = q[(size_t)c3 * 8 + lane];

    float d0, d1, d2, d3;
#if USE_SDOT4
    {
        int a0 = 0, a1 = 0, a2 = 0, a3 = 0;
        a0 = __builtin_amdgcn_sdot4((int)aw0.x, (int)bw0.x, a0, false);
        a1 = __builtin_amdgcn_sdot4((int)aw1.x, (int)bw1.x, a1, false);
        a2 = __builtin_amdgcn_sdot4((int)aw2.x, (int)bw2.x, a2, false);
        a3 = __builtin_amdgcn_sdot4((int)aw3.x, (int)bw3.x, a3, false);
        a0 = __builtin_amdgcn_sdot4((int)aw0.y, (int)bw0.y, a0, false);
        a1 = __builtin_amdgcn_sdot4((int)aw1.y, (int)bw1.y, a1, false);
        a2 = __builtin_amdgcn_sdot4((int)aw2.y, (int)bw2.y, a2, false);
        a3 = __builtin_amdgcn_sdot4((int)aw3.y, (int)bw3.y, a3, false);
        a0 = __builtin_amdgcn_sdot4((int)aw0.z, (int)bw0.z, a0, false);
        a1 = __builtin_amdgcn_sdot4((int)aw1.z, (int)bw1.z, a1, false);
        a2 = __builtin_amdgcn_sdot4((int)aw2.z, (int)bw2.z, a2, false);
        a3 = __builtin_amdgcn_sdot4((int)aw3.z, (int)bw3.z, a3, false);
        a0 = __builtin_amdgcn_sdot4((int)aw0.w, (int)bw0.w, a0, false);
        a1 = __builtin_amdgcn_sdot4((int)aw1.w, (int)bw1.w, a1, false);
        a2 = __builtin_amdgcn_sdot4((int)aw2.w, (int)bw2.w, a2, false);
        a3 = __builtin_amdgcn_sdot4((int)aw3.w, (int)bw3.w, a3, false);
#pragma unroll
        for (int o = 4; o > 0; o >>= 1) {
            a0 += __shfl_xor(a0, o, 8);
            a1 += __shfl_xor(a1, o, 8);
            a2 += __shfl_xor(a2, o, 8);
            a3 += __shfl_xor(a3, o, 8);
        }
        d0 = (float)a0 * (1.0f / 16129.0f);
        d1 = (float)a1 * (1.0f / 16129.0f);
        d2 = (float)a2 * (1.0f / 16129.0f);
        d3 = (float)a3 * (1.0f / 16129.0f);
    }
#else
    {
        float f0 = 0.f, f1 = 0.f, f2 = 0.f, f3 = 0.f;
        const unsigned int* ap0 = (const unsigned int*)&aw0;
        const unsigned int* bp0 = (const unsigned int*)&bw0;
        const unsigned int* ap1 = (const unsigned int*)&aw1;
        const unsigned int* bp1 = (const unsigned int*)&bw1;
        const unsigned int* ap2 = (const unsigned int*)&aw2;
        const unsigned int* bp2 = (const unsigned int*)&bw2;
        const unsigned int* ap3 = (const unsigned int*)&aw3;
        const unsigned int* bp3 = (const unsigned int*)&bw3;
#pragma unroll
        for (int i = 0; i < 4; i++) {
            v2f x, y;
            x = __builtin_amdgcn_cvt_pk_f32_fp8((int)ap0[i], false);
            y = __builtin_amdgcn_cvt_pk_f32_fp8((int)bp0[i], false);
            f0 = fmaf(x.x, y.x, f0); f0 = fmaf(x.y, y.y, f0);
            x = __builtin_amdgcn_cvt_pk_f32_fp8((int)ap0[i], true);
            y = __builtin_amdgcn_cvt_pk_f32_fp8((int)bp0[i], true);
            f0 = fmaf(x.x, y.x, f0); f0 = fmaf(x.y, y.y, f0);
            x = __builtin_amdgcn_cvt_pk_f32_fp8((int)ap1[i], false);
            y = __builtin_amdgcn_cvt_pk_f32_fp8((int)bp1[i], false);
            f1 = fmaf(x.x, y.x, f1); f1 = fmaf(x.y, y.y, f1);
            x = __builtin_amdgcn_cvt_pk_f32_fp8((int)ap1[i], true);
            y = __builtin_amdgcn_cvt_pk_f32_fp8((int)bp1[i], true);
            f1 = fmaf(x.x, y.x, f1); f1 = fmaf(x.y, y.y, f1);
            x = __builtin_amdgcn_cvt_pk_f32_fp8((int)ap2[i], false);
            y = __builtin_amdgcn_cvt_pk_f32_fp8((int)bp2[i], false);
            f2 = fmaf(x.x, y.x, f2); f2 = fmaf(x.y, y.y, f2);
            x = __builtin_amdgcn_cvt_pk_f32_fp8((int)ap2[i], true);
            y = __builtin_amdgcn_cvt_pk_f32_fp8((int)bp2[i], true);
            f2 = fmaf(x.x, y.x, f2); f2 = fmaf(x.y, y.y, f2);
            x = __builtin_amdgcn_cvt_pk_f32_fp8((int)ap3[i], false);
            y = __builtin_amdgcn_cvt_pk_f32_fp8((int)bp3[i], false);
            f3 = fmaf(x.x, y.x, f3); f3 = fmaf(x.y, y.y, f3);
            x = __builtin_amdgcn_cvt_pk_f32_fp8((int)ap3[i], true);
            y = __builtin_amdgcn_cvt_pk_f32_fp8((int)bp3[i], true);
            f3 = fmaf(x.x, y.x, f3); f3 = fmaf(x.y, y.y, f3);
        }
#pragma unroll
        for (int o = 4; o > 0; o >>= 1) {
            f0 += __shfl_xor(f0, o, 8);
            f1 += __shfl_xor(f1, o, 8);
            f2 += __shfl_xor(f2, o, 8);
            f3 += __shfl_xor(f3, o, 8);
        }
        d0 = f0; d1 = f1; d2 = f2; d3 = f3;
    }
#endif
    bool p0 = d0 > SCREEN_LO, p1 = d1 > SCREEN_LO;
    bool p2 = d2 > SCREEN_LO, p3 = d3 > SCREEN_LO;

    // --- tier 2: branchless-speculative. Non-passing edges read node 0's
    //     row (stays L2-hot), so all loads issue with no serialization. ---
    int ra0 = p0 ? r0 : 0, rb0 = p0 ? c0 : 0;
    int ra1 = p1 ? r1 : 0, rb1 = p1 ? c1 : 0;
    int ra2 = p2 ? r2 : 0, rb2 = p2 ? c2 : 0;
    int ra3 = p3 ? r3 : 0, rb3 = p3 ? c3 : 0;
    const v4f* f16 = (const v4f*)fn16;     // 16 v4f per node row
    v4f A00 = f16[(size_t)ra0 * 16 + lane];
    v4f A01 = f16[(size_t)ra0 * 16 + lane + 8];
    v4f B00 = f16[(size_t)rb0 * 16 + lane];
    v4f B01 = f16[(size_t)rb0 * 16 + lane + 8];
    v4f A10 = f16[(size_t)ra1 * 16 + lane];
    v4f A11 = f16[(size_t)ra1 * 16 + lane + 8];
    v4f B10 = f16[(size_t)rb1 * 16 + lane];
    v4f B11 = f16[(size_t)rb1 * 16 + lane + 8];
    v4f A20 = f16[(size_t)ra2 * 16 + lane];
    v4f A21 = f16[(size_t)ra2 * 16 + lane + 8];
    v4f B20 = f16[(size_t)rb2 * 16 + lane];
    v4f B21 = f16[(size_t)rb2 * 16 + lane + 8];
    v4f A30 = f16[(size_t)ra3 * 16 + lane];
    v4f A31 = f16[(size_t)ra3 * 16 + lane + 8];
    v4f B30 = f16[(size_t)rb3 * 16 + lane];
    v4f B31 = f16[(size_t)rb3 * 16 + lane + 8];

    float dh0 = 0.f, dh1 = 0.f, dh2 = 0.f, dh3 = 0.f;
#if USE_FDOT2
#define DOT16(acc, X, Y)                                                     \
    {                                                                        \
        const h2v* xp = (const h2v*)&(X);                                    \
        const h2v* yp = (const h2v*)&(Y);                                    \
        acc = __builtin_amdgcn_fdot2(xp[0], yp[0], acc, false);              \
        acc = __builtin_amdgcn_fdot2(xp[1], yp[1], acc, false);              \
        acc = __builtin_amdgcn_fdot2(xp[2], yp[2], acc, false);              \
        acc = __builtin_amdgcn_fdot2(xp[3], yp[3], acc, false);              \
    }
#else
#define DOT16(acc, X, Y)                                                     \
    {                                                                        \
        const __half2* xp = (const __half2*)&(X);                            \
        const __half2* yp = (const __half2*)&(Y);                            \
        for (int i_ = 0; i_ < 4; i_++) {                                     \
            float2 xa = __half22float2(xp[i_]);                              \
            float2 ya = __half22float2(yp[i_]);                              \
            acc = fmaf(xa.x, ya.x, acc);                                     \
            acc = fmaf(xa.y, ya.y, acc);                                     \
        }                                                                    \
    }
#endif
    DOT16(dh0, A00, B00) DOT16(dh0, A01, B01)
    DOT16(dh1, A10, B10) DOT16(dh1, A11, B11)
    DOT16(dh2, A20, B20) DOT16(dh2, A21, B21)
    DOT16(dh3, A30, B30) DOT16(dh3, A31, B31)
#pragma unroll
    for (int o = 4; o > 0; o >>= 1) {
        dh0 += __shfl_xor(dh0, o, 8);
        dh1 += __shfl_xor(dh1, o, 8);
        dh2 += __shfl_xor(dh2, o, 8);
        dh3 += __shfl_xor(dh3, o, 8);
    }

    // --- tier 3: exact fp32 rescue in the fp16 uncertainty band (rare) ---
    if (p0 && fabsf(dh0 - SIM_THRESH) < BAND_EPS) {
        const v4f* fr = (const v4f*)(feat + (size_t)r0 * D_FEAT);
        const v4f* fc = (const v4f*)(feat + (size_t)c0 * D_FEAT);
        float dd = 0.0f;
#pragma unroll
        for (int qq = 0; qq < 4; qq++) {
            v4f av = fr[lane + qq * 8], bv = fc[lane + qq * 8];
            dd += av.x * bv.x + av.y * bv.y + av.z * bv.z + av.w * bv.w;
        }
#pragma unroll
        for (int o = 4; o > 0; o >>= 1) dd += __shfl_xor(dd, o, 8);
        dh0 = dd * inv_nrm[r0] * inv_nrm[c0];
    }
    if (p1 && fabsf(dh1 - SIM_THRESH) < BAND_EPS) {
        const v4f* fr = (const v4f*)(feat + (size_t)r1 * D_FEAT);
        const v4f* fc = (const v4f*)(feat + (size_t)c1 * D_FEAT);
        float dd = 0.0f;
#pragma unroll
        for (int qq = 0; qq < 4; qq++) {
            v4f av = fr[lane + qq * 8], bv = fc[lane + qq * 8];
            dd += av.x * bv.x + av.y * bv.y + av.z * bv.z + av.w * bv.w;
        }
#pragma unroll
        for (int o = 4; o > 0; o >>= 1) dd += __shfl_xor(dd, o, 8);
        dh1 = dd * inv_nrm[r1] * inv_nrm[c1];
    }
    if (p2 && fabsf(dh2 - SIM_THRESH) < BAND_EPS) {
        const v4f* fr = (const v4f*)(feat + (size_t)r2 * D_FEAT);
        const v4f* fc = (const v4f*)(feat + (size_t)c2 * D_FEAT);
        float dd = 0.0f;
#pragma unroll
        for (int qq = 0; qq < 4; qq++) {
            v4f av = fr[lane + qq * 8], bv = fc[lane + qq * 8];
            dd += av.x * bv.x + av.y * bv.y + av.z * bv.z + av.w * bv.w;
        }
#pragma unroll
        for (int o = 4; o > 0; o >>= 1) dd += __shfl_xor(dd, o, 8);
        dh2 = dd * inv_nrm[r2] * inv_nrm[c2];
    }
    if (p3 && fabsf(dh3 - SIM_THRESH) < BAND_EPS) {
        const v4f* fr = (const v4f*)(feat + (size_t)r3 * D_FEAT);
        const v4f* fc = (const v4f*)(feat + (size_t)c3 * D_FEAT);
        float dd = 0.0f;
#pragma unroll
        for (int qq = 0; qq < 4; qq++) {
            v4f av = fr[lane + qq * 8], bv = fc[lane + qq * 8];
            dd += av.x * bv.x + av.y * bv.y + av.z * bv.z + av.w * bv.w;
        }
#pragma unroll
        for (int o = 4; o > 0; o >>= 1) dd += __shfl_xor(dd, o, 8);
        dh3 = dd * inv_nrm[r3] * inv_nrm[c3];
    }

    float s0 = (p0 && dh0 >= SIM_THRESH) ? dh0 : 0.0f;
    float s1 = (p1 && dh1 >= SIM_THRESH) ? dh1 : 0.0f;
    float s2 = (p2 && dh2 >= SIM_THRESH) ? dh2 : 0.0f;
    float s3 = (p3 && dh3 >= SIM_THRESH) ? dh3 : 0.0f;

    // --- epilogue: lanes 0..3 each own one edge (parallel stores/atomics) ---
    if (lane < 4) {
        float sv = (lane == 0) ? s0 : (lane == 1) ? s1 : (lane == 2) ? s2 : s3;
        int   rv = (lane == 0) ? r0 : (lane == 1) ? r1 : (lane == 2) ? r2 : r3;
        sim_out[e0 + lane] = sv;
        if (sv != 0.0f) {
            atomicAdd(&row_sum[rv], sv);
            atomicAdd(&degree[rv], 1.0f);
        }
    }
}

// ===========================================================================
// K3: epilogue — normalize, diagonal lam, exp, gate blend, clamp.
// 4 edges/thread, nontemporal vector streams (clang ext_vector types only).
// ===========================================================================
__global__ void edge_out_kernel(const int* __restrict__ row,
                                const int* __restrict__ col,
                                const float* __restrict__ sim,
                                const float* __restrict__ row_sum,
                                const float* __restrict__ degree,
                                const float* __restrict__ ew,
                                const float* __restrict__ gate,
                                float* __restrict__ out) {
    int t = blockIdx.x * blockDim.x + threadIdx.x;
    if (t >= N_EDGE / 4) return;
    v4i r4 = __builtin_nontemporal_load((const v4i*)row + t);
    v4i c4 = __builtin_nontemporal_load((const v4i*)col + t);
    v4f s4 = __builtin_nontemporal_load((const v4f*)sim + t);
    v4f w4 = __builtin_nontemporal_load((const v4f*)ew + t);
    float gv = gate[0];
    float og = 1.0f - gv;
    v4f o4;
#pragma unroll
    for (int i = 0; i < 4; i++) {
        int   ri = r4[i];
        float rs = row_sum[ri];
        float att = s4[i] / ((rs > 0.0f) ? rs : 1.0f);
        if (ri == c4[i]) att += 1.0f / (degree[ri] + 1.0f);
        o4[i] = fmaxf(gv * w4[i] + og * expf(att), 0.0f);
    }
    __builtin_nontemporal_store(o4, (v4f*)out + t);
}

// ===========================================================================
// Fallback (pure fp32) if ws too small.
// ===========================================================================
__global__ void inv_norm_kernel(const float* __restrict__ feat,
                                float* __restrict__ inv_nrm,
                                float* __restrict__ row_sum,
                                float* __restrict__ degree) {
    int g = blockIdx.x * blockDim.x + threadIdx.x;
    if (g < N_NODE) { row_sum[g] = 0.0f; degree[g] = 0.0f; }
    int node = g >> 5;
    int lane = g & 31;
    if (node >= N_NODE) return;
    float4 v = ((const float4*)(feat + (size_t)node * D_FEAT))[lane];
    float ss = v.x * v.x + v.y * v.y + v.z * v.z + v.w * v.w;
#pragma unroll
    for (int o = 16; o > 0; o >>= 1) ss += __shfl_down(ss, o, 32);
    if (lane == 0) inv_nrm[node] = 1.0f / fmaxf(sqrtf(ss), 1e-12f);
}

__global__ void edge_sim_kernel(const int* __restrict__ row,
                                const int* __restrict__ col,
                                const float* __restrict__ feat,
                                const float* __restrict__ inv_nrm,
                                float* __restrict__ sim_out,
                                float* __restrict__ row_sum,
                                float* __restrict__ degree) {
    int g = blockIdx.x * blockDim.x + threadIdx.x;
    int edge = g >> 5;
    int lane = g & 31;
    if (edge >= N_EDGE) return;
    int r = row[edge];
    int c = col[edge];
    float4 a = ((const float4*)(feat + (size_t)r * D_FEAT))[lane];
    float4 b = ((const float4*)(feat + (size_t)c * D_FEAT))[lane];
    float d = a.x * b.x + a.y * b.y + a.z * b.z + a.w * b.w;
#pragma unroll
    for (int o = 16; o > 0; o >>= 1) d += __shfl_down(d, o, 32);
    if (lane == 0) {
        float s = d * inv_nrm[r] * inv_nrm[c];
        if (s < SIM_THRESH) s = 0.0f;
        sim_out[edge] = s;
        if (s != 0.0f) {
            atomicAdd(&row_sum[r], s);
            atomicAdd(&degree[r], 1.0f);
        }
    }
}

// ===========================================================================
// Launch — 3 dispatches. Journal constraints:
//  - grid.sync ~600us on MI355X (R3 of prior session): never fuse across the
//    reduction. CSR/bucket permutation costs more than it wins (R5/R6).
//  - R2: 3x VALU cut in K2 = zero delta -> K2 not issue-bound.
//  - R3: nt on fn16/feat = -2us regression (reverted). K2 profile: 43.8us,
//    34% HBM, 17.5% VALU -> latency/MLP-bound -> EPT=4 restructure (this rd).
//  - Fills (268MB ws re-poison, ~44us @76% peak) dominate the rest of the
//    window — harness machinery, not addressable.
// ===========================================================================
extern "C" void kernel_launch(void* const* d_in, const int* in_sizes, int n_in,
                              void* d_out, int out_size, void* d_ws, size_t ws_size,
                              hipStream_t stream) {
    const int*   edge_index = (const int*)d_in[0];   // [2, E]: row then col
    const float* ew         = (const float*)d_in[1];
    const float* feat       = (const float*)d_in[2];
    const float* gate       = (const float*)d_in[3];
    float*       out        = (float*)d_out;

    const int* row = edge_index;
    const int* col = edge_index + N_EDGE;

    // ws layout: row_sum[N] | degree[N] | inv_nrm[N] | sim[E]
    //            | fn16[N*128 halves] | qtab[N*32 uints]
    float* row_sum = (float*)d_ws;
    float* degree  = row_sum + N_NODE;
    float* inv_nrm = degree + N_NODE;
    float* sim     = inv_nrm + N_NODE;
    __half* fn16   = (__half*)(sim + N_EDGE);
    unsigned int* qtab = (unsigned int*)(fn16 + (size_t)N_NODE * D_FEAT);

    size_t need = (size_t)(3 * N_NODE + N_EDGE) * 4
                + (size_t)N_NODE * D_FEAT * 2
                + (size_t)N_NODE * D_FEAT;

    const int block = 256;

    if (ws_size >= need) {
        {
            long long threads = (long long)N_NODE * 32;
            prep_kernel<<<(int)((threads + block - 1) / block), block, 0, stream>>>(
                feat, inv_nrm, fn16, qtab, row_sum, degree);
        }
        {
            long long threads = (long long)(N_EDGE / 4) * 8;   // 8 lanes per 4-edge group
            edge_sim8_kernel<<<(int)((threads + block - 1) / block), block, 0, stream>>>(
                row, col, feat, inv_nrm, fn16, qtab, sim, row_sum, degree);
        }
        {
            int threads = N_EDGE / 4;
            edge_out_kernel<<<(threads + block - 1) / block, block, 0, stream>>>(
                row, col, sim, row_sum, degree, ew, gate, out);
        }
    } else {
        {
            long long threads = (long long)N_NODE * 32;
            inv_norm_kernel<<<(int)((threads + block - 1) / block), block, 0, stream>>>(
                feat, inv_nrm, row_sum, degree);
        }
        {
            long long threads = (long long)N_EDGE * 32;
            edge_sim_kernel<<<(int)((threads + block - 1) / block), block, 0, stream>>>(
                row, col, feat, inv_nrm, sim, row_sum, degree);
        }
        {
            int threads = N_EDGE / 4;
            edge_out_kernel<<<(threads + block - 1) / block, block, 0, stream>>>(
                row, col, sim, row_sum, degree, ew, gate, out);
        }
    }
}